// Round 1
// baseline (234.454 us; speedup 1.0000x reference)
//
#include <hip/hip_runtime.h>
#include <hip/hip_bf16.h>
#include <stdint.h>

// out = tril(Q K^T) * scale @ V  (no softmax), Q/K/V = x @ W^T + b
// B=4, N=2048, D=1024, all f32 in/out; internal compute bf16 MFMA w/ f32 accum.

typedef __attribute__((ext_vector_type(4))) float f32x4;
typedef __attribute__((ext_vector_type(8))) short bf16x8s;
typedef __attribute__((ext_vector_type(4))) short bf16x4s;

__device__ __forceinline__ short f2bf(float f) {
  union { float f; unsigned u; } v; v.f = f;
  return (short)((v.u + 0x7FFFu + ((v.u >> 16) & 1u)) >> 16);  // RNE
}

// ---------------- cast f32 -> bf16, vectorized ----------------
__global__ void cast_f32_bf16(const float* __restrict__ in, short* __restrict__ out, int n4) {
  int idx = blockIdx.x * blockDim.x + threadIdx.x;
  int stride = gridDim.x * blockDim.x;
  for (int i = idx; i < n4; i += stride) {
    f32x4 v = ((const f32x4*)in)[i];
    bf16x4s o;
    o[0] = f2bf(v[0]); o[1] = f2bf(v[1]); o[2] = f2bf(v[2]); o[3] = f2bf(v[3]);
    ((bf16x4s*)out)[i] = o;
  }
}

// ---------------- NT GEMM: C[m,n] = sum_k A[m,k] * B[n,k] ----------------
// MODE 0: bf16 out + bias (Q/K projection)
// MODE 1: bf16 out TRANSPOSED per batch (Vt[e][n]) + bias (V projection)
// MODE 2: bf16 out, causal mask + scale (scores), skip tiles with tx>ty
// MODE 3: f32 out, causal K-extent (PV)
#define BM 128
#define BN 128
#define BKK 32

template <int MODE>
__global__ __launch_bounds__(256) void gemm_nt(
    const short* __restrict__ A, const short* __restrict__ B,
    const float* __restrict__ bias, void* __restrict__ C,
    int M, int N, int K, int lda, int ldb, int ldc,
    long long sA, long long sB, long long sC, float scale) {
  const int tx = blockIdx.x, ty = blockIdx.y, bz = blockIdx.z;
  if (MODE == 2 && tx > ty) return;  // strictly-upper tile: never read downstream
  int Kend = K;
  if (MODE == 3) { int ke = (ty + 1) * BM; if (ke < Kend) Kend = ke; }

  const short* Ab = A + (long long)bz * sA;
  const short* Bb = B + (long long)bz * sB;

  __shared__ short As[BM * BKK];
  __shared__ short Bs[BN * BKK];

  const int tid = threadIdx.x;
  const int wid = tid >> 6, lane = tid & 63;
  const int wm = wid >> 1, wn = wid & 1;          // 2x2 waves, 64x64 each
  const int kq = lane >> 4, r16 = lane & 15;      // MFMA fragment coords
  const int srow = lane >> 2, scol = (lane & 3) * 8;  // staging coords

  f32x4 acc[4][4];
#pragma unroll
  for (int i = 0; i < 4; ++i)
#pragma unroll
    for (int j = 0; j < 4; ++j) { f32x4 z = {0.f, 0.f, 0.f, 0.f}; acc[i][j] = z; }

  for (int k0 = 0; k0 < Kend; k0 += BKK) {
    __syncthreads();  // previous compute done before LDS overwrite
#pragma unroll
    for (int p = 0; p < 2; ++p) {
      int c = p * 4 + wid;  // 0..7, wave-uniform
      const short* ga = Ab + (ty * BM + c * 16 + srow) * lda + k0 + scol;
      __builtin_amdgcn_global_load_lds(
          (const __attribute__((address_space(1))) void*)ga,
          (__attribute__((address_space(3))) void*)&As[c * 512], 16, 0, 0);
      const short* gb = Bb + (tx * BN + c * 16 + srow) * ldb + k0 + scol;
      __builtin_amdgcn_global_load_lds(
          (const __attribute__((address_space(1))) void*)gb,
          (__attribute__((address_space(3))) void*)&Bs[c * 512], 16, 0, 0);
    }
    asm volatile("s_waitcnt vmcnt(0)" ::: "memory");
    __syncthreads();

    bf16x8s af[4], bfr[4];
#pragma unroll
    for (int i = 0; i < 4; ++i)
      af[i] = *(const bf16x8s*)&As[(wm * 64 + i * 16 + r16) * BKK + kq * 8];
#pragma unroll
    for (int j = 0; j < 4; ++j)
      bfr[j] = *(const bf16x8s*)&Bs[(wn * 64 + j * 16 + r16) * BKK + kq * 8];
#pragma unroll
    for (int i = 0; i < 4; ++i)
#pragma unroll
      for (int j = 0; j < 4; ++j)
        acc[i][j] = __builtin_amdgcn_mfma_f32_16x16x32_bf16(af[i], bfr[j], acc[i][j], 0, 0, 0);
  }

  const int row0 = ty * BM + wm * 64;
  const int col0 = tx * BN + wn * 64;

  if (MODE == 0) {
    short* Cb = (short*)C + (long long)bz * sC;
#pragma unroll
    for (int i = 0; i < 4; ++i) {
#pragma unroll
      for (int j = 0; j < 4; ++j) {
        int col = col0 + j * 16 + r16;
        float bv = bias[col];
#pragma unroll
        for (int r = 0; r < 4; ++r) {
          int row = row0 + i * 16 + kq * 4 + r;
          Cb[(size_t)row * ldc + col] = f2bf(acc[i][j][r] + bv);
        }
      }
    }
  } else if (MODE == 1) {
    // Vt[b][e][n], b derived from global row (2048 rows per batch)
    short* Cb = (short*)C;
#pragma unroll
    for (int i = 0; i < 4; ++i) {
      int rowg = row0 + i * 16 + kq * 4;  // 4 consecutive m
      int b = rowg >> 11, n0 = rowg & 2047;
      long long base = (long long)b * (1024LL * 2048LL);
#pragma unroll
      for (int j = 0; j < 4; ++j) {
        int col = col0 + j * 16 + r16;  // e
        float bv = bias[col];
        bf16x4s o;
#pragma unroll
        for (int r = 0; r < 4; ++r) o[r] = f2bf(acc[i][j][r] + bv);
        *(bf16x4s*)&Cb[base + (long long)col * 2048 + n0] = o;
      }
    }
  } else if (MODE == 2) {
    short* Cb = (short*)C + (long long)bz * sC;
#pragma unroll
    for (int i = 0; i < 4; ++i) {
#pragma unroll
      for (int j = 0; j < 4; ++j) {
        int col = col0 + j * 16 + r16;
#pragma unroll
        for (int r = 0; r < 4; ++r) {
          int row = row0 + i * 16 + kq * 4 + r;
          float v = (col <= row) ? acc[i][j][r] * scale : 0.0f;
          Cb[(size_t)row * ldc + col] = f2bf(v);
        }
      }
    }
  } else {
    float* Cb = (float*)C + (long long)bz * sC;
#pragma unroll
    for (int i = 0; i < 4; ++i) {
#pragma unroll
      for (int j = 0; j < 4; ++j) {
        int col = col0 + j * 16 + r16;
#pragma unroll
        for (int r = 0; r < 4; ++r) {
          int row = row0 + i * 16 + kq * 4 + r;
          Cb[(size_t)row * ldc + col] = acc[i][j][r];
        }
      }
    }
  }
}

extern "C" void kernel_launch(void* const* d_in, const int* in_sizes, int n_in,
                              void* d_out, int out_size, void* d_ws, size_t ws_size,
                              hipStream_t stream) {
  const float* x  = (const float*)d_in[0];
  const float* Wq = (const float*)d_in[1];
  const float* bq = (const float*)d_in[2];
  const float* Wk = (const float*)d_in[3];
  const float* bk = (const float*)d_in[4];
  const float* Wv = (const float*)d_in[5];
  const float* bv = (const float*)d_in[6];

  const int B = 4, Ns = 2048, D = 1024;
  const int Mtot = B * Ns;  // 8192
  const long long MB = 1LL << 20;

  char* ws = (char*)d_ws;
  short* Qb  = (short*)(ws + 0 * MB);    // 16 MB bf16 Q [8192,1024]
  short* Kb  = (short*)(ws + 16 * MB);   // 16 MB bf16 K
  short* Vt  = (short*)(ws + 32 * MB);   // 16 MB bf16 V^T per batch [4][1024][2048]
  short* xb  = (short*)(ws + 48 * MB);   // 16 MB bf16 x  (dead after projections)
  short* Wqb = (short*)(ws + 64 * MB);   // 2 MB each
  short* Wkb = (short*)(ws + 66 * MB);
  short* Wvb = (short*)(ws + 68 * MB);
  short* Sb  = (short*)(ws + 48 * MB);   // 32 MB scores, reuses xb/W region (stream-ordered)
  // total ws requirement: 80 MB

  // 1. casts
  cast_f32_bf16<<<2048, 256, 0, stream>>>(x, xb, (Mtot * D) / 4);
  cast_f32_bf16<<<512, 256, 0, stream>>>(Wq, Wqb, (D * D) / 4);
  cast_f32_bf16<<<512, 256, 0, stream>>>(Wk, Wkb, (D * D) / 4);
  cast_f32_bf16<<<512, 256, 0, stream>>>(Wv, Wvb, (D * D) / 4);

  // 2. projections: [8192,1024] = xb [8192,1024] @ W^T [1024,1024]
  dim3 g1(D / BN, Mtot / BM, 1);  // (8, 64)
  gemm_nt<0><<<g1, 256, 0, stream>>>(xb, Wqb, bq, Qb, Mtot, D, D, D, D, D, 0, 0, 0, 1.0f);
  gemm_nt<0><<<g1, 256, 0, stream>>>(xb, Wkb, bk, Kb, Mtot, D, D, D, D, D, 0, 0, 0, 1.0f);
  gemm_nt<1><<<g1, 256, 0, stream>>>(xb, Wvb, bv, Vt, Mtot, D, D, D, D, 0, 0, 0, 0, 1.0f);

  // 3. scores: per batch S[2048,2048] = tril(Q K^T) * 1/32, bf16
  dim3 g2(Ns / BN, Ns / BM, B);  // (16, 16, 4); tx>ty tiles skipped
  gemm_nt<2><<<g2, 256, 0, stream>>>(Qb, Kb, nullptr, Sb, Ns, Ns, D, D, D, Ns,
                                     (long long)Ns * D, (long long)Ns * D,
                                     (long long)Ns * Ns, 0.03125f);

  // 4. PV: per batch O[2048,1024] = S @ Vt^T (NT), K-extent = (qt+1)*128
  dim3 g3(D / BN, Ns / BM, B);  // (8, 16, 4)
  gemm_nt<3><<<g3, 256, 0, stream>>>(Sb, Vt, nullptr, d_out, Ns, D, Ns, Ns, Ns, D,
                                     (long long)Ns * Ns, (long long)D * Ns,
                                     (long long)Ns * D, 1.0f);
}

// Round 3
// 185.585 us; speedup vs baseline: 1.2633x; 1.2633x over previous
//
#include <hip/hip_runtime.h>
#include <hip/hip_bf16.h>
#include <stdint.h>

// out = tril(Q K^T) * scale @ V  (no softmax), Q/K/V = x @ W^T + b
// B=4, N=2048, D=1024, all f32 in/out; internal compute bf16 MFMA w/ f32 accum.

typedef __attribute__((ext_vector_type(4))) float f32x4;
typedef __attribute__((ext_vector_type(8))) short bf16x8s;
typedef __attribute__((ext_vector_type(4))) short bf16x4s;

__device__ __forceinline__ short f2bf(float f) {
  union { float f; unsigned u; } v; v.f = f;
  return (short)((v.u + 0x7FFFu + ((v.u >> 16) & 1u)) >> 16);  // RNE
}

// ---------------- fused cast f32 -> bf16 (x + Wq/Wk/Wv -> xb + Wcat) ----------------
__global__ void cast_all(const float* __restrict__ x, const float* __restrict__ wq,
                         const float* __restrict__ wk, const float* __restrict__ wv,
                         short* __restrict__ xb, short* __restrict__ wcat) {
  const int n4x = 1 << 21;          // 8192*1024/4
  const int n4w = 1 << 18;          // 1024*1024/4
  const int total = n4x + 3 * n4w;
  int idx = blockIdx.x * blockDim.x + threadIdx.x;
  int stride = gridDim.x * blockDim.x;
  for (int i = idx; i < total; i += stride) {
    f32x4 v;
    short* dst;
    if (i < n4x) {
      v = ((const f32x4*)x)[i];
      dst = xb + (size_t)i * 4;
    } else {
      int j = i - n4x;
      int sel = j >> 18, off = j & (n4w - 1);
      const float* src = (sel == 0) ? wq : (sel == 1) ? wk : wv;
      v = ((const f32x4*)src)[off];
      dst = wcat + (size_t)j * 4;
    }
    bf16x4s o;
    o[0] = f2bf(v[0]); o[1] = f2bf(v[1]); o[2] = f2bf(v[2]); o[3] = f2bf(v[3]);
    *(bf16x4s*)dst = o;
  }
}

#define BM 128
#define BN 128
#define BKK 32

// shared K-loop body: stages A/B 128x32 bf16 tiles, accumulates 4x4 16x16 frags
#define GEMM_BODY(Ab, lda, Bb, ldb, KEND)                                              \
  for (int k0 = 0; k0 < (KEND); k0 += BKK) {                                           \
    __syncthreads();                                                                   \
    _Pragma("unroll") for (int p = 0; p < 2; ++p) {                                    \
      int c = p * 4 + wid;                                                             \
      const short* ga = (Ab) + ((size_t)(arow0 + c * 16 + srow)) * (lda) + k0 + scol;  \
      __builtin_amdgcn_global_load_lds(                                                \
          (const __attribute__((address_space(1))) void*)ga,                           \
          (__attribute__((address_space(3))) void*)&As[c * 512], 16, 0, 0);            \
      const short* gb = (Bb) + ((size_t)(brow0 + c * 16 + srow)) * (ldb) + k0 + scol;  \
      __builtin_amdgcn_global_load_lds(                                                \
          (const __attribute__((address_space(1))) void*)gb,                           \
          (__attribute__((address_space(3))) void*)&Bs[c * 512], 16, 0, 0);            \
    }                                                                                  \
    asm volatile("s_waitcnt vmcnt(0)" ::: "memory");                                   \
    __syncthreads();                                                                   \
    bf16x8s af[4], bfr[4];                                                             \
    _Pragma("unroll") for (int i = 0; i < 4; ++i)                                      \
        af[i] = *(const bf16x8s*)&As[(wm * 64 + i * 16 + r16) * BKK + kq * 8];         \
    _Pragma("unroll") for (int j = 0; j < 4; ++j)                                      \
        bfr[j] = *(const bf16x8s*)&Bs[(wn * 64 + j * 16 + r16) * BKK + kq * 8];        \
    _Pragma("unroll") for (int i = 0; i < 4; ++i)                                      \
        _Pragma("unroll") for (int j = 0; j < 4; ++j)                                  \
            acc[i][j] = __builtin_amdgcn_mfma_f32_16x16x32_bf16(af[i], bfr[j],         \
                                                                acc[i][j], 0, 0, 0);   \
  }

#define GEMM_PREAMBLE                                                   \
  __shared__ short As[BM * BKK];                                        \
  __shared__ short Bs[BN * BKK];                                        \
  const int tid = threadIdx.x;                                          \
  const int wid = tid >> 6, lane = tid & 63;                            \
  const int wm = wid >> 1, wn = wid & 1;                                \
  const int kq = lane >> 4, r16 = lane & 15;                            \
  const int srow = lane >> 2, scol = (lane & 3) * 8;                    \
  f32x4 acc[4][4];                                                      \
  _Pragma("unroll") for (int i = 0; i < 4; ++i)                         \
      _Pragma("unroll") for (int j = 0; j < 4; ++j) {                   \
    f32x4 z = {0.f, 0.f, 0.f, 0.f};                                     \
    acc[i][j] = z;                                                      \
  }

// ---------------- fused QKV projection ----------------
// C[8192, 3072] = xb[8192,1024] @ Wcat[3072,1024]^T ; epilogue routes by segment:
// seg0 -> Qb (+bq), seg1 -> Kb (+bk), seg2 -> Vt transposed (+bv)
__global__ __launch_bounds__(256) void gemm_qkv(
    const short* __restrict__ A, const short* __restrict__ B,
    const float* __restrict__ bq, const float* __restrict__ bk,
    const float* __restrict__ bv, short* __restrict__ Qb,
    short* __restrict__ Kb, short* __restrict__ Vt) {
  // XCD-bijective swizzle over 1536 blocks (1536 % 8 == 0)
  int id = blockIdx.x;
  int swz = (id & 7) * 192 + (id >> 3);
  const int tx = swz % 24, ty = swz / 24;
  const int arow0 = ty * BM, brow0 = tx * BN;

  GEMM_PREAMBLE
  GEMM_BODY(A, 1024, B, 1024, 1024)

  const int row0 = ty * BM + wm * 64;
  const int col0g = tx * BN + wn * 64;
  const int seg = col0g >> 10;        // block spans 128 cols, all in one segment
  const int col0 = col0g & 1023;
  const float* bias = (seg == 0) ? bq : (seg == 1) ? bk : bv;

  if (seg < 2) {
    short* Cb = (seg == 0) ? Qb : Kb;
#pragma unroll
    for (int i = 0; i < 4; ++i) {
#pragma unroll
      for (int j = 0; j < 4; ++j) {
        int col = col0 + j * 16 + r16;
        float bvv = bias[col];
#pragma unroll
        for (int r = 0; r < 4; ++r) {
          int row = row0 + i * 16 + kq * 4 + r;
          Cb[(size_t)row * 1024 + col] = f2bf(acc[i][j][r] + bvv);
        }
      }
    }
  } else {
    // Vt[b][e][n]
#pragma unroll
    for (int i = 0; i < 4; ++i) {
      int rowg = row0 + i * 16 + kq * 4;
      int b = rowg >> 11, n0 = rowg & 2047;
      long long base = (long long)b * (1024LL * 2048LL);
#pragma unroll
      for (int j = 0; j < 4; ++j) {
        int col = col0 + j * 16 + r16;
        float bvv = bias[col];
        bf16x4s o;
#pragma unroll
        for (int r = 0; r < 4; ++r) o[r] = f2bf(acc[i][j][r] + bvv);
        *(bf16x4s*)&Vt[base + (long long)col * 2048 + n0] = o;
      }
    }
  }
}

// ---------------- scores: S = tril(Q K^T) * scale, bf16, triangular-packed grid ----
// grid: (136, 1, B); blockIdx.x = packed lower-tri tile index
__global__ __launch_bounds__(256) void gemm_scores(
    const short* __restrict__ Q, const short* __restrict__ K,
    short* __restrict__ S, float scale) {
  const int bz = blockIdx.z;
  // decode packed triangular index -> (ty, tx), tx <= ty
  int i = blockIdx.x;
  int ty = (int)((sqrtf(8.0f * i + 1.0f) - 1.0f) * 0.5f);
  while ((ty + 1) * (ty + 2) / 2 <= i) ++ty;
  while (ty * (ty + 1) / 2 > i) --ty;
  const int tx = i - ty * (ty + 1) / 2;

  const short* Ab = Q + (long long)bz * (2048LL * 1024LL);
  const short* Bb = K + (long long)bz * (2048LL * 1024LL);
  const int arow0 = ty * BM, brow0 = tx * BN;

  GEMM_PREAMBLE
  GEMM_BODY(Ab, 1024, Bb, 1024, 1024)

  short* Cb = S + (long long)bz * (2048LL * 2048LL);
  const int row0 = ty * BM + wm * 64;
  const int col0 = tx * BN + wn * 64;
#pragma unroll
  for (int i2 = 0; i2 < 4; ++i2) {
#pragma unroll
    for (int j = 0; j < 4; ++j) {
      int col = col0 + j * 16 + r16;
#pragma unroll
      for (int r = 0; r < 4; ++r) {
        int row = row0 + i2 * 16 + kq * 4 + r;
        float v = (col <= row) ? acc[i2][j][r] * scale : 0.0f;
        Cb[(size_t)row * 2048 + col] = f2bf(v);
      }
    }
  }
}

// ---------------- PV: O = S @ Vt^T (NT), causal K-extent, longest-first ----------
// grid: (8, 16, B); logical ty reversed so heavy blocks dispatch first
__global__ __launch_bounds__(256) void gemm_pv(
    const short* __restrict__ S, const short* __restrict__ Vt,
    float* __restrict__ O) {
  const int tx = blockIdx.x, bz = blockIdx.z;
  const int ty = (int)gridDim.y - 1 - (int)blockIdx.y;  // longest-first
  const int Kend = (ty + 1) * BM;

  const short* Ab = S + (long long)bz * (2048LL * 2048LL);
  const short* Bb = Vt + (long long)bz * (1024LL * 2048LL);
  const int arow0 = ty * BM, brow0 = tx * BN;

  GEMM_PREAMBLE
  GEMM_BODY(Ab, 2048, Bb, 2048, Kend)

  float* Cb = O + (long long)bz * (2048LL * 1024LL);
  const int row0 = ty * BM + wm * 64;
  const int col0 = tx * BN + wn * 64;
#pragma unroll
  for (int i2 = 0; i2 < 4; ++i2) {
#pragma unroll
    for (int j = 0; j < 4; ++j) {
      int col = col0 + j * 16 + r16;
#pragma unroll
      for (int r = 0; r < 4; ++r) {
        int row = row0 + i2 * 16 + kq * 4 + r;
        Cb[(size_t)row * 1024 + col] = acc[i2][j][r];
      }
    }
  }
}

extern "C" void kernel_launch(void* const* d_in, const int* in_sizes, int n_in,
                              void* d_out, int out_size, void* d_ws, size_t ws_size,
                              hipStream_t stream) {
  const float* x  = (const float*)d_in[0];
  const float* Wq = (const float*)d_in[1];
  const float* bq = (const float*)d_in[2];
  const float* Wk = (const float*)d_in[3];
  const float* bk = (const float*)d_in[4];
  const float* Wv = (const float*)d_in[5];
  const float* bv = (const float*)d_in[6];

  const int B = 4;
  const long long MB = 1LL << 20;

  char* ws = (char*)d_ws;
  short* Qb   = (short*)(ws + 0 * MB);   // 16 MB bf16 Q [8192,1024]
  short* Kb   = (short*)(ws + 16 * MB);  // 16 MB bf16 K
  short* Vt   = (short*)(ws + 32 * MB);  // 16 MB bf16 V^T [4][1024][2048]
  short* xb   = (short*)(ws + 48 * MB);  // 16 MB bf16 x     (dead after QKV)
  short* Wcat = (short*)(ws + 64 * MB);  // 6 MB  bf16 [Wq;Wk;Wv] (dead after QKV)
  short* Sb   = (short*)(ws + 48 * MB);  // 32 MB scores, reuses xb/Wcat (stream-ordered)
  // total ws requirement: 80 MB

  // 1. fused casts
  cast_all<<<2048, 256, 0, stream>>>(x, Wq, Wk, Wv, xb, Wcat);

  // 2. fused QKV projection: [8192,3072] = xb @ Wcat^T ; 1536 blocks
  gemm_qkv<<<1536, 256, 0, stream>>>(xb, Wcat, bq, bk, bv, Qb, Kb, Vt);

  // 3. scores: per batch S = tril(Q K^T) / 32, packed triangular grid
  dim3 g2(136, 1, B);
  gemm_scores<<<g2, 256, 0, stream>>>(Qb, Kb, Sb, 0.03125f);

  // 4. PV: per batch O = S @ Vt^T, causal K-extent, longest-first
  dim3 g3(8, 16, B);
  gemm_pv<<<g3, 256, 0, stream>>>(Sb, Vt, (float*)d_out);
}